// Round 3
// baseline (603.014 us; speedup 1.0000x reference)
//
#include <hip/hip_runtime.h>
#include <math.h>

#define NODES   62
#define DEG     16
#define EPN     17                  // edges per node incl. self-loop
#define EPG     (NODES*EPN)         // 1054
#define NGRAPH  4096
#define NTOT    (NGRAPH*NODES)      // 253952
#define FIN     32
#define HIDC    64
#define XS      72                  // bf16 row stride for xl/xr (144B, 9-word quads -> banks spread)

__device__ __forceinline__ unsigned short bf16r(float f) {   // f32 -> bf16 RNE
    unsigned int u = __float_as_uint(f);
    u += 0x7fffu + ((u >> 16) & 1u);
    return (unsigned short)(u >> 16);
}
__device__ __forceinline__ float blo(unsigned int d) { return __uint_as_float(d << 16); }
__device__ __forceinline__ float bhi(unsigned int d) { return __uint_as_float(d & 0xffff0000u); }
__device__ __forceinline__ float lrelu(float z) { return fmaxf(z, 0.2f*z); }

// ---------------------------------------------------------------------------
// Kernel A: GATv2 layer 1, one block (256 thr) per 62-node graph.
// Edge-parallel alpha (no shuffles), quad-parallel softmax, bf16 xl/xr in LDS.
// ---------------------------------------------------------------------------
__global__ __launch_bounds__(256, 4) void gat1_kernel(
    const float* __restrict__ x, const int* __restrict__ esrc,
    const float* __restrict__ Wl, const float* __restrict__ bl,
    const float* __restrict__ Wr, const float* __restrict__ br,
    const float* __restrict__ att, const float* __restrict__ bias,
    float* __restrict__ h, float* __restrict__ part)
{
    __shared__ float4 xs4[NODES][FIN/4];                       // 7936 B
    __shared__ unsigned int aw[EPG];                           // 4216 B: alpha f32 -> (s<<16)|bf16(w')
    __shared__ unsigned short eS[EPG];                         // 2108 B: local src per edge
    __shared__ __align__(16) unsigned short xlb[NODES*XS];     // 8928 B
    __shared__ __align__(16) unsigned short xrb[NODES*XS];     // 8928 B
    __shared__ float red[2][4][16][4];                         // 2048 B

    const int tid   = threadIdx.x;
    const int g     = blockIdx.x;
    const int nbase = g * NODES;

    // ---- stage x ----
    const float4* xg = (const float4*)x + (size_t)nbase * (FIN/4);
    for (int i = tid; i < NODES*(FIN/4); i += 256)
        xs4[i >> 3][i & 7] = xg[i];

    // ---- stage edge table (s per edge; edge i = node i/17, slot i%17; slot 16 = self) ----
    const int* eg = esrc + (size_t)nbase * DEG;
    for (int i = tid; i < EPG; i += 256) {
        const unsigned int d = ((unsigned int)i * 61681u) >> 20;   // i/17 exact for i<2^16
        const int j = i - (int)d * EPN;
        const int s = (j < DEG) ? (eg[(int)d*DEG + j] - nbase) : (int)d;
        eS[i] = (unsigned short)s;
    }

    // ---- per-thread weight columns (channel c) ----
    const int c = tid & 63;
    float wl[FIN], wr[FIN];
#pragma unroll
    for (int k = 0; k < FIN; ++k) { wl[k] = Wl[k*HIDC + c]; wr[k] = Wr[k*HIDC + c]; }
    const float blc = bl[c], brc = br[c];

    __syncthreads();

    // ---- xl, xr -> LDS (bf16) ----
    for (int idx = tid; idx < NODES*HIDC; idx += 256) {
        const int node = idx >> 6;                 // idx&63 == c
        float al = blc, ar = brc;
#pragma unroll
        for (int q = 0; q < FIN/4; ++q) {
            const float4 v = xs4[node][q];
            al += v.x*wl[4*q] + v.y*wl[4*q+1] + v.z*wl[4*q+2] + v.w*wl[4*q+3];
            ar += v.x*wr[4*q] + v.y*wr[4*q+1] + v.z*wr[4*q+2] + v.w*wr[4*q+3];
        }
        xlb[node*XS + c] = bf16r(al);
        xrb[node*XS + c] = bf16r(ar);
    }

    // att -> 32 packed bf16-pair dwords (loaded here; latency hidden by barrier)
    unsigned int attp[32];
#pragma unroll
    for (int k = 0; k < 32; ++k)
        attp[k] = (unsigned int)bf16r(att[2*k]) | ((unsigned int)bf16r(att[2*k+1]) << 16);

    __syncthreads();

    // ---- alpha: one lane per edge, serial over 64 channels ----
    for (int i = tid; i < EPG; i += 256) {
        const unsigned int d = ((unsigned int)i * 61681u) >> 20;
        const int s = eS[i];
        const uint4* lp = (const uint4*)(xlb + s*XS);
        const uint4* rp = (const uint4*)(xrb + (int)d*XS);
        float acc = 0.f;
#pragma unroll
        for (int q = 0; q < 8; ++q) {
            const uint4 lv = lp[q];
            const uint4 rv = rp[q];
            float z;
            z = blo(lv.x)+blo(rv.x); acc += blo(attp[4*q+0]) * lrelu(z);
            z = bhi(lv.x)+bhi(rv.x); acc += bhi(attp[4*q+0]) * lrelu(z);
            z = blo(lv.y)+blo(rv.y); acc += blo(attp[4*q+1]) * lrelu(z);
            z = bhi(lv.y)+bhi(rv.y); acc += bhi(attp[4*q+1]) * lrelu(z);
            z = blo(lv.z)+blo(rv.z); acc += blo(attp[4*q+2]) * lrelu(z);
            z = bhi(lv.z)+bhi(rv.z); acc += bhi(attp[4*q+2]) * lrelu(z);
            z = blo(lv.w)+blo(rv.w); acc += blo(attp[4*q+3]) * lrelu(z);
            z = bhi(lv.w)+bhi(rv.w); acc += bhi(attp[4*q+3]) * lrelu(z);
        }
        aw[i] = __float_as_uint(acc);
    }
    __syncthreads();

    // ---- softmax per node: 4-lane quads, edges split 4/4/4/5 ----
    {
        const int node = tid >> 2, sub = tid & 3;
        if (node < NODES) {
            const int base = node*EPN + sub*4;
            float a0 = __uint_as_float(aw[base+0]);
            float a1 = __uint_as_float(aw[base+1]);
            float a2 = __uint_as_float(aw[base+2]);
            float a3 = __uint_as_float(aw[base+3]);
            const bool h5 = (sub == 3);
            float a4 = h5 ? __uint_as_float(aw[base+4]) : -1e30f;
            float m = fmaxf(fmaxf(fmaxf(a0,a1), fmaxf(a2,a3)), a4);
            m = fmaxf(m, __shfl_xor(m,1));
            m = fmaxf(m, __shfl_xor(m,2));
            a0 = __expf(a0-m); a1 = __expf(a1-m); a2 = __expf(a2-m); a3 = __expf(a3-m);
            a4 = h5 ? __expf(a4-m) : 0.f;
            float ss = a0+a1+a2+a3+a4;
            ss += __shfl_xor(ss,1);
            ss += __shfl_xor(ss,2);
            const float inv = 1.f/(ss + 1e-16f);
            aw[base+0] = ((unsigned int)eS[base+0]<<16) | bf16r(a0*inv);
            aw[base+1] = ((unsigned int)eS[base+1]<<16) | bf16r(a1*inv);
            aw[base+2] = ((unsigned int)eS[base+2]<<16) | bf16r(a2*inv);
            aw[base+3] = ((unsigned int)eS[base+3]<<16) | bf16r(a3*inv);
            if (h5) aw[base+4] = ((unsigned int)eS[base+4]<<16) | bf16r(a4*inv);
        }
    }
    __syncthreads();

    // ---- aggregation: 16 lanes/node x 4 channels; w+src in one broadcast word ----
    const int wave = tid >> 6;
    const int lane = tid & 63;
    const int grp  = lane >> 4;
    const int l16  = lane & 15;
    const int cl   = l16 * 4;

    const float4 biasv = *(const float4*)(bias + cl);

    float sx=0.f, sy=0.f, sz=0.f, sw=0.f;
    float qx=0.f, qy=0.f, qz=0.f, qw=0.f;

#pragma unroll
    for (int pass = 0; pass < 4; ++pass) {
        const int node = pass*16 + wave*4 + grp;
        if (node < NODES) {
            float ax=0.f, ay=0.f, az=0.f, a3=0.f;
#pragma unroll
            for (int e = 0; e < EPN; ++e) {
                const unsigned int p = aw[node*EPN + e];
                const float w = __uint_as_float(p << 16);
                const int s = (int)(p >> 16);
                const uint2 xv = *(const uint2*)(xlb + s*XS + cl);
                ax += w*blo(xv.x); ay += w*bhi(xv.x);
                az += w*blo(xv.y); a3 += w*bhi(xv.y);
            }
            ax += biasv.x; ay += biasv.y; az += biasv.z; a3 += biasv.w;
            float4 hv; hv.x=ax; hv.y=ay; hv.z=az; hv.w=a3;
            *(float4*)(h + (size_t)(nbase + node)*HIDC + cl) = hv;
            sx+=ax; sy+=ay; sz+=az; sw+=a3;
            qx+=ax*ax; qy+=ay*ay; qz+=az*az; qw+=a3*a3;
        }
    }

    // ---- BN partials ----
    sx += __shfl_xor(sx,16); sx += __shfl_xor(sx,32);
    sy += __shfl_xor(sy,16); sy += __shfl_xor(sy,32);
    sz += __shfl_xor(sz,16); sz += __shfl_xor(sz,32);
    sw += __shfl_xor(sw,16); sw += __shfl_xor(sw,32);
    qx += __shfl_xor(qx,16); qx += __shfl_xor(qx,32);
    qy += __shfl_xor(qy,16); qy += __shfl_xor(qy,32);
    qz += __shfl_xor(qz,16); qz += __shfl_xor(qz,32);
    qw += __shfl_xor(qw,16); qw += __shfl_xor(qw,32);
    if (lane < 16) {
        red[0][wave][l16][0]=sx; red[0][wave][l16][1]=sy; red[0][wave][l16][2]=sz; red[0][wave][l16][3]=sw;
        red[1][wave][l16][0]=qx; red[1][wave][l16][1]=qy; red[1][wave][l16][2]=qz; red[1][wave][l16][3]=qw;
    }
    __syncthreads();
    if (tid < 128) {                       // part is g-major: coalesced 512B store
        const int t = tid & 63, sel = tid >> 6, li = t >> 2, co = t & 3;
        const float s = red[sel][0][li][co] + red[sel][1][li][co]
                      + red[sel][2][li][co] + red[sel][3][li][co];
        part[(size_t)g*128 + tid] = s;
    }
}

// ---------------------------------------------------------------------------
// Kernel B: reduce BN partials (coalesced), fold BN into layer-2 weights.
// fw[0:64]=sc*Wl2, fw[64:128]=sc*Wr2, fw[128]=bl2', fw[129]=br2'
// ---------------------------------------------------------------------------
__global__ __launch_bounds__(1024) void bnfold_kernel(
    const float* __restrict__ part,
    const float* __restrict__ gamma, const float* __restrict__ beta,
    const float* __restrict__ Wl2, const float* __restrict__ bl2,
    const float* __restrict__ Wr2, const float* __restrict__ br2,
    float* __restrict__ fw)
{
    __shared__ float red2[16][128];
    __shared__ float gs[128];
    __shared__ float tmp[128];
    const int tid = threadIdx.x;
    const int wave = tid >> 6, lane = tid & 63;

    float a0 = 0.f, a1 = 0.f;
    for (int k = wave; k < NGRAPH; k += 16) {
        const float2 v = *(const float2*)(part + (size_t)k*128 + lane*2);
        a0 += v.x; a1 += v.y;
    }
    red2[wave][lane*2]   = a0;
    red2[wave][lane*2+1] = a1;
    __syncthreads();
    if (tid < 128) {
        float s = 0.f;
#pragma unroll
        for (int w = 0; w < 16; ++w) s += red2[w][tid];
        gs[tid] = s;
    }
    __syncthreads();
    if (tid < HIDC) {
        const float invN = 1.f / (float)NTOT;
        const float mu  = gs[tid] * invN;
        const float var = gs[HIDC + tid] * invN - mu*mu;
        const float sc  = gamma[tid] * rsqrtf(var + 1e-5f);
        const float sh  = beta[tid] - mu * sc;
        fw[tid]        = sc * Wl2[tid];
        fw[HIDC + tid] = sc * Wr2[tid];
        tmp[tid]        = sh * Wl2[tid];
        tmp[HIDC + tid] = sh * Wr2[tid];
    }
    __syncthreads();
    if (tid < 64) {
        float aL = tmp[tid], aR = tmp[64 + tid];
#pragma unroll
        for (int msk = 1; msk < 64; msk <<= 1) {
            aL += __shfl_xor(aL, msk);
            aR += __shfl_xor(aR, msk);
        }
        if (tid == 0) { fw[128] = aL + bl2[0]; fw[129] = aR + br2[0]; }
    }
}

// ---------------------------------------------------------------------------
// Kernel C: GATv2 layer 2 (scalar features) + exact GELU. Quad-parallel edges.
// ---------------------------------------------------------------------------
__global__ __launch_bounds__(256, 4) void gat2_kernel(
    const float* __restrict__ h, const int* __restrict__ esrc,
    const float* __restrict__ fw, const float* __restrict__ att2,
    const float* __restrict__ bias2, float* __restrict__ out)
{
    __shared__ float xl2s[64], xr2s[64];
    __shared__ float wls[HIDC], wrs[HIDC];
    __shared__ unsigned short srcs[NODES*DEG];

    const int tid   = threadIdx.x;
    const int g     = blockIdx.x;
    const int nbase = g * NODES;

    if (tid < HIDC) { wls[tid] = fw[tid]; wrs[tid] = fw[HIDC + tid]; }
    const int* eg = esrc + (size_t)nbase * DEG;
    for (int i = tid; i < NODES*DEG; i += 256)
        srcs[i] = (unsigned short)(eg[i] - nbase);
    __syncthreads();

    // xl2/xr2 per node: 4 lanes x 16 channels
    if (tid < NODES*4) {
        const int node = tid >> 2, sub = tid & 3;
        const float4* hp = (const float4*)(h + (size_t)(nbase + node)*HIDC + sub*16);
        float al = 0.f, ar = 0.f;
#pragma unroll
        for (int q = 0; q < 4; ++q) {
            const float4 v = hp[q];
            const int cb = sub*16 + q*4;
            al += v.x*wls[cb] + v.y*wls[cb+1] + v.z*wls[cb+2] + v.w*wls[cb+3];
            ar += v.x*wrs[cb] + v.y*wrs[cb+1] + v.z*wrs[cb+2] + v.w*wrs[cb+3];
        }
        al += __shfl_xor(al,1); al += __shfl_xor(al,2);
        ar += __shfl_xor(ar,1); ar += __shfl_xor(ar,2);
        if (sub == 0) { xl2s[node] = al + fw[128]; xr2s[node] = ar + fw[129]; }
    }
    __syncthreads();

    // attention + aggregation: quads, edges split 4/4/4/(4+self)
    {
        const int node = tid >> 2, sub = tid & 3;
        if (node < NODES) {
            const float xr  = xr2s[node];
            const float a2v = att2[0];
            const int jb = sub*4;
            const int s0 = srcs[node*DEG + jb+0];
            const int s1 = srcs[node*DEG + jb+1];
            const int s2 = srcs[node*DEG + jb+2];
            const int s3 = srcs[node*DEG + jb+3];
            const bool h5 = (sub == 3);
            const float x0 = xl2s[s0], x1 = xl2s[s1], x2 = xl2s[s2], x3 = xl2s[s3];
            const float x4 = xl2s[node];                    // self loop
            const float v0 = lrelu(x0+xr)*a2v;
            const float v1 = lrelu(x1+xr)*a2v;
            const float v2 = lrelu(x2+xr)*a2v;
            const float v3 = lrelu(x3+xr)*a2v;
            const float v4 = h5 ? lrelu(x4+xr)*a2v : -1e30f;
            float m = fmaxf(fmaxf(fmaxf(v0,v1), fmaxf(v2,v3)), v4);
            m = fmaxf(m, __shfl_xor(m,1));
            m = fmaxf(m, __shfl_xor(m,2));
            const float e0 = __expf(v0-m), e1 = __expf(v1-m);
            const float e2 = __expf(v2-m), e3 = __expf(v3-m);
            const float e4 = h5 ? __expf(v4-m) : 0.f;
            float ss = e0+e1+e2+e3+e4;
            float ac = e0*x0 + e1*x1 + e2*x2 + e3*x3 + e4*x4;
            ss += __shfl_xor(ss,1); ss += __shfl_xor(ss,2);
            ac += __shfl_xor(ac,1); ac += __shfl_xor(ac,2);
            if (sub == 0) {
                const float o = ac/(ss + 1e-16f) + bias2[0];
                out[(size_t)g*NODES + node] = 0.5f*o*(1.f + erff(o*0.70710678118654752f));
            }
        }
    }
}

extern "C" void kernel_launch(void* const* d_in, const int* in_sizes, int n_in,
                              void* d_out, int out_size, void* d_ws, size_t ws_size,
                              hipStream_t stream) {
    const float* x     = (const float*)d_in[0];
    const int*   edge  = (const int*)d_in[1];     // [2,E]; src = first E
    const float* Wl1   = (const float*)d_in[2];
    const float* bl1   = (const float*)d_in[3];
    const float* Wr1   = (const float*)d_in[4];
    const float* br1   = (const float*)d_in[5];
    const float* att1  = (const float*)d_in[6];
    const float* bias1 = (const float*)d_in[7];
    const float* gamma = (const float*)d_in[8];
    const float* beta  = (const float*)d_in[9];
    const float* Wl2   = (const float*)d_in[10];
    const float* bl2   = (const float*)d_in[11];
    const float* Wr2   = (const float*)d_in[12];
    const float* br2   = (const float*)d_in[13];
    const float* att2  = (const float*)d_in[14];
    const float* bias2 = (const float*)d_in[15];
    float* out = (float*)d_out;

    float* h    = (float*)d_ws;                       // NTOT*64 floats
    float* part = h + (size_t)NTOT * HIDC;            // 4096*128 floats, g-major
    float* fw   = part + (size_t)128 * NGRAPH;        // 130 floats

    gat1_kernel<<<NGRAPH, 256, 0, stream>>>(x, edge, Wl1, bl1, Wr1, br1,
                                            att1, bias1, h, part);
    bnfold_kernel<<<1, 1024, 0, stream>>>(part, gamma, beta, Wl2, bl2, Wr2, br2, fw);
    gat2_kernel<<<NGRAPH, 256, 0, stream>>>(h, edge, fw, att2, bias2, out);
}

// Round 4
// 286.459 us; speedup vs baseline: 2.1051x; 2.1051x over previous
//
#include <hip/hip_runtime.h>
#include <math.h>

#define NODES   62
#define DEG     16
#define EPN     17                  // edges per node incl. self-loop
#define EPG     (NODES*EPN)         // 1054
#define NGRAPH  4096
#define NTOT    (NGRAPH*NODES)      // 253952
#define FIN     32
#define HIDC    64
#define XS      72                  // bf16 row stride for xl/xr (144B, 9-word quads -> banks spread)

__device__ __forceinline__ unsigned short bf16r(float f) {   // f32 -> bf16 RNE
    unsigned int u = __float_as_uint(f);
    u += 0x7fffu + ((u >> 16) & 1u);
    return (unsigned short)(u >> 16);
}
__device__ __forceinline__ float blo(unsigned int d) { return __uint_as_float(d << 16); }
__device__ __forceinline__ float bhi(unsigned int d) { return __uint_as_float(d & 0xffff0000u); }
__device__ __forceinline__ float lrelu(float z) { return fmaxf(z, 0.2f*z); }

// ---------------------------------------------------------------------------
// Kernel A: GATv2 layer 1, one block (256 thr) per 62-node graph.
// Edge-parallel alpha (no shuffles), quad-parallel softmax, bf16 xl/xr in LDS.
// launch_bounds (256,2): do NOT cap VGPR below the ~100-reg live set (round-2
// lesson: (256,4) forced 64 VGPR -> scratch spills -> 1.4GB HBM traffic).
// ---------------------------------------------------------------------------
__global__ __launch_bounds__(256, 2) void gat1_kernel(
    const float* __restrict__ x, const int* __restrict__ esrc,
    const float* __restrict__ Wl, const float* __restrict__ bl,
    const float* __restrict__ Wr, const float* __restrict__ br,
    const float* __restrict__ att, const float* __restrict__ bias,
    float* __restrict__ h, float* __restrict__ part)
{
    __shared__ float4 xs4[NODES][FIN/4];                       // 7936 B
    __shared__ unsigned int aw[EPG];                           // 4216 B: alpha f32 -> (s<<16)|bf16(w')
    __shared__ unsigned short eS[EPG];                         // 2108 B: local src per edge
    __shared__ __align__(16) unsigned short xlb[NODES*XS];     // 8928 B
    __shared__ __align__(16) unsigned short xrb[NODES*XS];     // 8928 B
    __shared__ __align__(16) unsigned int attL[32];            // 128 B: packed bf16 att pairs
    __shared__ float red[2][4][16][4];                         // 2048 B

    const int tid   = threadIdx.x;
    const int g     = blockIdx.x;
    const int nbase = g * NODES;

    // ---- stage x ----
    const float4* xg = (const float4*)x + (size_t)nbase * (FIN/4);
    for (int i = tid; i < NODES*(FIN/4); i += 256)
        xs4[i >> 3][i & 7] = xg[i];

    // ---- stage edge table (edge i = node i/17, slot i%17; slot 16 = self) ----
    const int* eg = esrc + (size_t)nbase * DEG;
    for (int i = tid; i < EPG; i += 256) {
        const unsigned int d = ((unsigned int)i * 61681u) >> 20;   // i/17 exact for i<2^16
        const int j = i - (int)d * EPN;
        const int s = (j < DEG) ? (eg[(int)d*DEG + j] - nbase) : (int)d;
        eS[i] = (unsigned short)s;
    }

    // ---- packed att -> LDS (keeps 32 dwords OUT of registers) ----
    if (tid < 32)
        attL[tid] = (unsigned int)bf16r(att[2*tid]) | ((unsigned int)bf16r(att[2*tid+1]) << 16);

    // ---- per-thread weight columns (channel c) ----
    const int c = tid & 63;
    float wl[FIN], wr[FIN];
#pragma unroll
    for (int k = 0; k < FIN; ++k) { wl[k] = Wl[k*HIDC + c]; wr[k] = Wr[k*HIDC + c]; }
    const float blc = bl[c], brc = br[c];

    __syncthreads();

    // ---- xl, xr -> LDS (bf16) ----
    for (int idx = tid; idx < NODES*HIDC; idx += 256) {
        const int node = idx >> 6;                 // idx&63 == c
        float al = blc, ar = brc;
#pragma unroll
        for (int q = 0; q < FIN/4; ++q) {
            const float4 v = xs4[node][q];
            al += v.x*wl[4*q] + v.y*wl[4*q+1] + v.z*wl[4*q+2] + v.w*wl[4*q+3];
            ar += v.x*wr[4*q] + v.y*wr[4*q+1] + v.z*wr[4*q+2] + v.w*wr[4*q+3];
        }
        xlb[node*XS + c] = bf16r(al);
        xrb[node*XS + c] = bf16r(ar);
    }
    __syncthreads();

    // ---- alpha: one lane per edge, serial over 64 channels ----
    for (int i = tid; i < EPG; i += 256) {
        const unsigned int d = ((unsigned int)i * 61681u) >> 20;
        const int s = eS[i];
        const uint4* lp = (const uint4*)(xlb + s*XS);
        const uint4* rp = (const uint4*)(xrb + (int)d*XS);
        float acc = 0.f;
#pragma unroll
        for (int q = 0; q < 8; ++q) {
            const uint4 lv = lp[q];
            const uint4 rv = rp[q];
            const uint4 ap = ((const uint4*)attL)[q];          // broadcast, conflict-free
            float z;
            z = blo(lv.x)+blo(rv.x); acc += blo(ap.x) * lrelu(z);
            z = bhi(lv.x)+bhi(rv.x); acc += bhi(ap.x) * lrelu(z);
            z = blo(lv.y)+blo(rv.y); acc += blo(ap.y) * lrelu(z);
            z = bhi(lv.y)+bhi(rv.y); acc += bhi(ap.y) * lrelu(z);
            z = blo(lv.z)+blo(rv.z); acc += blo(ap.z) * lrelu(z);
            z = bhi(lv.z)+bhi(rv.z); acc += bhi(ap.z) * lrelu(z);
            z = blo(lv.w)+blo(rv.w); acc += blo(ap.w) * lrelu(z);
            z = bhi(lv.w)+bhi(rv.w); acc += bhi(ap.w) * lrelu(z);
        }
        aw[i] = __float_as_uint(acc);
    }
    __syncthreads();

    // ---- softmax per node: 4-lane quads, edges split 4/4/4/5 ----
    {
        const int node = tid >> 2, sub = tid & 3;
        if (node < NODES) {
            const int base = node*EPN + sub*4;
            float a0 = __uint_as_float(aw[base+0]);
            float a1 = __uint_as_float(aw[base+1]);
            float a2 = __uint_as_float(aw[base+2]);
            float a3 = __uint_as_float(aw[base+3]);
            const bool h5 = (sub == 3);
            float a4 = h5 ? __uint_as_float(aw[base+4]) : -1e30f;
            float m = fmaxf(fmaxf(fmaxf(a0,a1), fmaxf(a2,a3)), a4);
            m = fmaxf(m, __shfl_xor(m,1));
            m = fmaxf(m, __shfl_xor(m,2));
            a0 = __expf(a0-m); a1 = __expf(a1-m); a2 = __expf(a2-m); a3 = __expf(a3-m);
            a4 = h5 ? __expf(a4-m) : 0.f;
            float ss = a0+a1+a2+a3+a4;
            ss += __shfl_xor(ss,1);
            ss += __shfl_xor(ss,2);
            const float inv = 1.f/(ss + 1e-16f);
            aw[base+0] = ((unsigned int)eS[base+0]<<16) | bf16r(a0*inv);
            aw[base+1] = ((unsigned int)eS[base+1]<<16) | bf16r(a1*inv);
            aw[base+2] = ((unsigned int)eS[base+2]<<16) | bf16r(a2*inv);
            aw[base+3] = ((unsigned int)eS[base+3]<<16) | bf16r(a3*inv);
            if (h5) aw[base+4] = ((unsigned int)eS[base+4]<<16) | bf16r(a4*inv);
        }
    }
    __syncthreads();

    // ---- aggregation: 16 lanes/node x 4 channels; w+src in one broadcast word ----
    const int wave = tid >> 6;
    const int lane = tid & 63;
    const int grp  = lane >> 4;
    const int l16  = lane & 15;
    const int cl   = l16 * 4;

    const float4 biasv = *(const float4*)(bias + cl);

    float sx=0.f, sy=0.f, sz=0.f, sw=0.f;
    float qx=0.f, qy=0.f, qz=0.f, qw=0.f;

#pragma unroll
    for (int pass = 0; pass < 4; ++pass) {
        const int node = pass*16 + wave*4 + grp;
        if (node < NODES) {
            float ax=0.f, ay=0.f, az=0.f, a3=0.f;
#pragma unroll
            for (int e = 0; e < EPN; ++e) {
                const unsigned int p = aw[node*EPN + e];
                const float w = __uint_as_float(p << 16);
                const int s = (int)(p >> 16);
                const uint2 xv = *(const uint2*)(xlb + s*XS + cl);
                ax += w*blo(xv.x); ay += w*bhi(xv.x);
                az += w*blo(xv.y); a3 += w*bhi(xv.y);
            }
            ax += biasv.x; ay += biasv.y; az += biasv.z; a3 += biasv.w;
            float4 hv; hv.x=ax; hv.y=ay; hv.z=az; hv.w=a3;
            *(float4*)(h + (size_t)(nbase + node)*HIDC + cl) = hv;
            sx+=ax; sy+=ay; sz+=az; sw+=a3;
            qx+=ax*ax; qy+=ay*ay; qz+=az*az; qw+=a3*a3;
        }
    }

    // ---- BN partials ----
    sx += __shfl_xor(sx,16); sx += __shfl_xor(sx,32);
    sy += __shfl_xor(sy,16); sy += __shfl_xor(sy,32);
    sz += __shfl_xor(sz,16); sz += __shfl_xor(sz,32);
    sw += __shfl_xor(sw,16); sw += __shfl_xor(sw,32);
    qx += __shfl_xor(qx,16); qx += __shfl_xor(qx,32);
    qy += __shfl_xor(qy,16); qy += __shfl_xor(qy,32);
    qz += __shfl_xor(qz,16); qz += __shfl_xor(qz,32);
    qw += __shfl_xor(qw,16); qw += __shfl_xor(qw,32);
    if (lane < 16) {
        red[0][wave][l16][0]=sx; red[0][wave][l16][1]=sy; red[0][wave][l16][2]=sz; red[0][wave][l16][3]=sw;
        red[1][wave][l16][0]=qx; red[1][wave][l16][1]=qy; red[1][wave][l16][2]=qz; red[1][wave][l16][3]=qw;
    }
    __syncthreads();
    if (tid < 128) {                       // part g-major: coalesced 512B store
        const int t = tid & 63, sel = tid >> 6, li = t >> 2, co = t & 3;
        const float s = red[sel][0][li][co] + red[sel][1][li][co]
                      + red[sel][2][li][co] + red[sel][3][li][co];
        part[(size_t)g*128 + tid] = s;
    }
}

// ---------------------------------------------------------------------------
// Kernel B1: stage-1 BN reduce. 64 blocks x 256 thr; block b sums 64 graphs.
// ---------------------------------------------------------------------------
__global__ __launch_bounds__(256) void bnred_kernel(
    const float* __restrict__ part, float* __restrict__ part2)
{
    __shared__ float red[2][128];
    const int b = blockIdx.x;
    const int ch = threadIdx.x & 127, rg = threadIdx.x >> 7;
    float s = 0.f;
    for (int r = rg; r < 64; r += 2)
        s += part[((size_t)b*64 + r)*128 + ch];
    red[rg][ch] = s;
    __syncthreads();
    if (threadIdx.x < 128)
        part2[(size_t)b*128 + threadIdx.x] = red[0][threadIdx.x] + red[1][threadIdx.x];
}

// ---------------------------------------------------------------------------
// Kernel B2: final fold. part2[64][128] -> BN folded into layer-2 weights.
// fw[0:64]=sc*Wl2, fw[64:128]=sc*Wr2, fw[128]=bl2', fw[129]=br2'
// ---------------------------------------------------------------------------
__global__ __launch_bounds__(256) void bnfold_kernel(
    const float* __restrict__ part2,
    const float* __restrict__ gamma, const float* __restrict__ beta,
    const float* __restrict__ Wl2, const float* __restrict__ bl2,
    const float* __restrict__ Wr2, const float* __restrict__ br2,
    float* __restrict__ fw)
{
    __shared__ float hred[2][128];
    __shared__ float gs[128];
    __shared__ float tmp[128];
    const int tid = threadIdx.x;
    const int ch = tid & 127, hg = tid >> 7;
    float s = 0.f;
    for (int r = hg; r < 64; r += 2) s += part2[(size_t)r*128 + ch];
    hred[hg][ch] = s;
    __syncthreads();
    if (tid < 128) gs[tid] = hred[0][tid] + hred[1][tid];
    __syncthreads();
    if (tid < HIDC) {
        const float invN = 1.f / (float)NTOT;
        const float mu  = gs[tid] * invN;
        const float var = gs[HIDC + tid] * invN - mu*mu;
        const float sc  = gamma[tid] * rsqrtf(var + 1e-5f);
        const float sh  = beta[tid] - mu * sc;
        fw[tid]        = sc * Wl2[tid];
        fw[HIDC + tid] = sc * Wr2[tid];
        tmp[tid]        = sh * Wl2[tid];
        tmp[HIDC + tid] = sh * Wr2[tid];
    }
    __syncthreads();
    if (tid < 64) {
        float aL = tmp[tid], aR = tmp[64 + tid];
#pragma unroll
        for (int msk = 1; msk < 64; msk <<= 1) {
            aL += __shfl_xor(aL, msk);
            aR += __shfl_xor(aR, msk);
        }
        if (tid == 0) { fw[128] = aL + bl2[0]; fw[129] = aR + br2[0]; }
    }
}

// ---------------------------------------------------------------------------
// Kernel C: GATv2 layer 2 (scalar features) + exact GELU. Quad-parallel edges.
// ---------------------------------------------------------------------------
__global__ __launch_bounds__(256, 4) void gat2_kernel(
    const float* __restrict__ h, const int* __restrict__ esrc,
    const float* __restrict__ fw, const float* __restrict__ att2,
    const float* __restrict__ bias2, float* __restrict__ out)
{
    __shared__ float xl2s[64], xr2s[64];
    __shared__ float wls[HIDC], wrs[HIDC];
    __shared__ unsigned short srcs[NODES*DEG];

    const int tid   = threadIdx.x;
    const int g     = blockIdx.x;
    const int nbase = g * NODES;

    if (tid < HIDC) { wls[tid] = fw[tid]; wrs[tid] = fw[HIDC + tid]; }
    const int* eg = esrc + (size_t)nbase * DEG;
    for (int i = tid; i < NODES*DEG; i += 256)
        srcs[i] = (unsigned short)(eg[i] - nbase);
    __syncthreads();

    // xl2/xr2 per node: 4 lanes x 16 channels
    if (tid < NODES*4) {
        const int node = tid >> 2, sub = tid & 3;
        const float4* hp = (const float4*)(h + (size_t)(nbase + node)*HIDC + sub*16);
        float al = 0.f, ar = 0.f;
#pragma unroll
        for (int q = 0; q < 4; ++q) {
            const float4 v = hp[q];
            const int cb = sub*16 + q*4;
            al += v.x*wls[cb] + v.y*wls[cb+1] + v.z*wls[cb+2] + v.w*wls[cb+3];
            ar += v.x*wrs[cb] + v.y*wrs[cb+1] + v.z*wrs[cb+2] + v.w*wrs[cb+3];
        }
        al += __shfl_xor(al,1); al += __shfl_xor(al,2);
        ar += __shfl_xor(ar,1); ar += __shfl_xor(ar,2);
        if (sub == 0) { xl2s[node] = al + fw[128]; xr2s[node] = ar + fw[129]; }
    }
    __syncthreads();

    // attention + aggregation: quads, edges split 4/4/4/(4+self)
    {
        const int node = tid >> 2, sub = tid & 3;
        if (node < NODES) {
            const float xr  = xr2s[node];
            const float a2v = att2[0];
            const int jb = sub*4;
            const int s0 = srcs[node*DEG + jb+0];
            const int s1 = srcs[node*DEG + jb+1];
            const int s2 = srcs[node*DEG + jb+2];
            const int s3 = srcs[node*DEG + jb+3];
            const bool h5 = (sub == 3);
            const float x0 = xl2s[s0], x1 = xl2s[s1], x2 = xl2s[s2], x3 = xl2s[s3];
            const float x4 = xl2s[node];                    // self loop
            const float v0 = lrelu(x0+xr)*a2v;
            const float v1 = lrelu(x1+xr)*a2v;
            const float v2 = lrelu(x2+xr)*a2v;
            const float v3 = lrelu(x3+xr)*a2v;
            const float v4 = h5 ? lrelu(x4+xr)*a2v : -1e30f;
            float m = fmaxf(fmaxf(fmaxf(v0,v1), fmaxf(v2,v3)), v4);
            m = fmaxf(m, __shfl_xor(m,1));
            m = fmaxf(m, __shfl_xor(m,2));
            const float e0 = __expf(v0-m), e1 = __expf(v1-m);
            const float e2 = __expf(v2-m), e3 = __expf(v3-m);
            const float e4 = h5 ? __expf(v4-m) : 0.f;
            float ss = e0+e1+e2+e3+e4;
            float ac = e0*x0 + e1*x1 + e2*x2 + e3*x3 + e4*x4;
            ss += __shfl_xor(ss,1); ss += __shfl_xor(ss,2);
            ac += __shfl_xor(ac,1); ac += __shfl_xor(ac,2);
            if (sub == 0) {
                const float o = ac/(ss + 1e-16f) + bias2[0];
                out[(size_t)g*NODES + node] = 0.5f*o*(1.f + erff(o*0.70710678118654752f));
            }
        }
    }
}

extern "C" void kernel_launch(void* const* d_in, const int* in_sizes, int n_in,
                              void* d_out, int out_size, void* d_ws, size_t ws_size,
                              hipStream_t stream) {
    const float* x     = (const float*)d_in[0];
    const int*   edge  = (const int*)d_in[1];     // [2,E]; src = first E
    const float* Wl1   = (const float*)d_in[2];
    const float* bl1   = (const float*)d_in[3];
    const float* Wr1   = (const float*)d_in[4];
    const float* br1   = (const float*)d_in[5];
    const float* att1  = (const float*)d_in[6];
    const float* bias1 = (const float*)d_in[7];
    const float* gamma = (const float*)d_in[8];
    const float* beta  = (const float*)d_in[9];
    const float* Wl2   = (const float*)d_in[10];
    const float* bl2   = (const float*)d_in[11];
    const float* Wr2   = (const float*)d_in[12];
    const float* br2   = (const float*)d_in[13];
    const float* att2  = (const float*)d_in[14];
    const float* bias2 = (const float*)d_in[15];
    float* out = (float*)d_out;

    float* h     = (float*)d_ws;                      // NTOT*64 floats
    float* part  = h + (size_t)NTOT * HIDC;           // 4096*128 floats, g-major
    float* part2 = part + (size_t)128 * NGRAPH;       // 64*128 floats
    float* fw    = part2 + (size_t)64 * 128;          // 130 floats

    gat1_kernel<<<NGRAPH, 256, 0, stream>>>(x, edge, Wl1, bl1, Wr1, br1,
                                            att1, bias1, h, part);
    bnred_kernel<<<64, 256, 0, stream>>>(part, part2);
    bnfold_kernel<<<1, 256, 0, stream>>>(part2, gamma, beta, Wl2, bl2, Wr2, br2, fw);
    gat2_kernel<<<NGRAPH, 256, 0, stream>>>(h, edge, fw, att2, bias2, out);
}

// Round 6
// 241.223 us; speedup vs baseline: 2.4998x; 1.1875x over previous
//
#include <hip/hip_runtime.h>
#include <math.h>

#define NODES   62
#define DEG     16
#define EPN     17                  // edges per node incl. self-loop
#define EPG     (NODES*EPN)         // 1054
#define NGRAPH  4096
#define NTOT    (NGRAPH*NODES)      // 253952
#define FIN     32
#define HIDC    64
#define XS      72                  // bf16 row stride for xl/xr (144B = 9*16 -> b128 aligned)
#define WS      40                  // bf16 row stride for MFMA operand tiles (80B: 2-way banks)

typedef __attribute__((ext_vector_type(8))) short bf16x8;   // 8 bf16 = 4 VGPR (MFMA A/B frag)
typedef __attribute__((ext_vector_type(4))) float f32x4;    // MFMA C/D frag

__device__ __forceinline__ unsigned short bf16r(float f) {   // f32 -> bf16 RNE
    unsigned int u = __float_as_uint(f);
    u += 0x7fffu + ((u >> 16) & 1u);
    return (unsigned short)(u >> 16);
}
__device__ __forceinline__ float blo(unsigned int d) { return __uint_as_float(d << 16); }
__device__ __forceinline__ float bhi(unsigned int d) { return __uint_as_float(d & 0xffff0000u); }
__device__ __forceinline__ float lrelu(float z) { return fmaxf(z, 0.2f*z); }

// ---------------------------------------------------------------------------
// Kernel A: GATv2 layer 1, one block (256 thr) per 62-node graph.
// Phase a (x@Wl, x@Wr) on the MATRIX pipe (16x16x32 bf16 MFMA, K=32 -> 1 inst
// per tile); alpha edge-parallel on VALU with att held in 32 VGPRs; softmax
// quad-parallel; aggregation 16-lane/node. launch_bounds(256,3): VGPR cap
// ~168 >> ~100 live (round-2 lesson: never cap below the live set).
// ---------------------------------------------------------------------------
__global__ __launch_bounds__(256, 3) void gat1_kernel(
    const float* __restrict__ x, const int* __restrict__ esrc,
    const float* __restrict__ Wl, const float* __restrict__ bl,
    const float* __restrict__ Wr, const float* __restrict__ br,
    const float* __restrict__ att, const float* __restrict__ bias,
    float* __restrict__ h, float* __restrict__ part)
{
    __shared__ __align__(16) unsigned short xbf[64*WS];     // 5120 B: x bf16 [row][k]
    __shared__ __align__(16) unsigned short wlT[64*WS];     // 5120 B: Wl^T bf16 [col][k]
    __shared__ __align__(16) unsigned short wrT[64*WS];     // 5120 B
    __shared__ float blL[HIDC], brL[HIDC];                  // 512 B
    __shared__ __align__(16) unsigned int attL[32];         // 128 B packed bf16 pairs
    __shared__ unsigned short eS[EPG];                      // 2108 B local src per edge
    __shared__ unsigned int aw[EPG];                        // 4216 B alpha / (s<<16|w)
    __shared__ __align__(16) unsigned short xlb[64*XS];     // 9216 B
    __shared__ __align__(16) unsigned short xrb[64*XS];     // 9216 B
    __shared__ float red[2][4][16][4];                      // 2048 B   (total ~42 KB)

    const int tid   = threadIdx.x;
    const int g     = blockIdx.x;
    const int nbase = g * NODES;

    // ---- stage x -> bf16 LDS (rows 62,63 zeroed) ----
    {
        const float2* xg = (const float2*)(x + (size_t)nbase * FIN);
        for (int i = tid; i < 64*16; i += 256) {
            const int n = i >> 4, c2 = i & 15;
            unsigned int pk = 0u;
            if (n < NODES) {
                const float2 v = xg[i];
                pk = (unsigned int)bf16r(v.x) | ((unsigned int)bf16r(v.y) << 16);
            }
            ((unsigned int*)xbf)[n*(WS/2) + c2] = pk;
        }
    }
    // ---- stage Wl^T, Wr^T (B-frag layout: [col][k]) ----
    for (int i = tid; i < FIN*HIDC; i += 256) {
        const int k = i >> 6, c = i & 63;
        wlT[c*WS + k] = bf16r(Wl[i]);
        wrT[c*WS + k] = bf16r(Wr[i]);
    }
    if (tid < HIDC) { blL[tid] = bl[tid]; brL[tid] = br[tid]; }
    if (tid < 32)
        attL[tid] = (unsigned int)bf16r(att[2*tid]) | ((unsigned int)bf16r(att[2*tid+1]) << 16);

    // ---- stage edge table (edge i = node i/17, slot i%17; slot 16 = self) ----
    const int* eg = esrc + (size_t)nbase * DEG;
    for (int i = tid; i < EPG; i += 256) {
        const unsigned int d = ((unsigned int)i * 61681u) >> 20;   // i/17 exact
        const int j = i - (int)d * EPN;
        const int s = (j < DEG) ? (eg[(int)d*DEG + j] - nbase) : (int)d;
        eS[i] = (unsigned short)s;
    }
    __syncthreads();

    const int wv  = tid >> 6;
    const int l   = tid & 63;
    const int r16 = l & 15;
    const int kg  = l >> 4;

    // ---- phase a on MFMA: wave wv owns rows 16wv..16wv+15 of C[64,64] ----
    {
        const bf16x8 afr = *(const bf16x8*)(xbf + (wv*16 + r16)*WS + kg*8);
        const f32x4 zz = {0.f, 0.f, 0.f, 0.f};
        f32x4 aL[4], aR[4];
#pragma unroll
        for (int ct = 0; ct < 4; ++ct) {
            const bf16x8 bL = *(const bf16x8*)(wlT + (ct*16 + r16)*WS + kg*8);
            aL[ct] = __builtin_amdgcn_mfma_f32_16x16x32_bf16(afr, bL, zz, 0, 0, 0);
            const bf16x8 bR = *(const bf16x8*)(wrT + (ct*16 + r16)*WS + kg*8);
            aR[ct] = __builtin_amdgcn_mfma_f32_16x16x32_bf16(afr, bR, zz, 0, 0, 0);
        }
        // epilogue: D[row=4*kg+j][col=r16] per tile (m89-verified C/D map)
#pragma unroll
        for (int ct = 0; ct < 4; ++ct) {
            const int col = ct*16 + r16;
            const float bLc = blL[col], bRc = brL[col];
#pragma unroll
            for (int j = 0; j < 4; ++j) {
                const int row = wv*16 + kg*4 + j;
                xlb[row*XS + col] = bf16r(aL[ct][j] + bLc);
                xrb[row*XS + col] = bf16r(aR[ct][j] + bRc);
            }
        }
    }

    // att pairs -> 32 VGPRs (attL ready since barrier above)
    uint4 apr[8];
#pragma unroll
    for (int q = 0; q < 8; ++q) apr[q] = ((const uint4*)attL)[q];

    __syncthreads();

    // ---- alpha: one lane per edge, serial over 64 channels ----
    for (int i = tid; i < EPG; i += 256) {
        const unsigned int d = ((unsigned int)i * 61681u) >> 20;
        const int s = eS[i];
        const uint4* lp = (const uint4*)(xlb + s*XS);
        const uint4* rp = (const uint4*)(xrb + (int)d*XS);
        float acc = 0.f;
#pragma unroll
        for (int q = 0; q < 8; ++q) {
            const uint4 lv = lp[q];
            const uint4 rv = rp[q];
            const uint4 ap = apr[q];
            float z;
            z = blo(lv.x)+blo(rv.x); acc += blo(ap.x) * lrelu(z);
            z = bhi(lv.x)+bhi(rv.x); acc += bhi(ap.x) * lrelu(z);
            z = blo(lv.y)+blo(rv.y); acc += blo(ap.y) * lrelu(z);
            z = bhi(lv.y)+bhi(rv.y); acc += bhi(ap.y) * lrelu(z);
            z = blo(lv.z)+blo(rv.z); acc += blo(ap.z) * lrelu(z);
            z = bhi(lv.z)+bhi(rv.z); acc += bhi(ap.z) * lrelu(z);
            z = blo(lv.w)+blo(rv.w); acc += blo(ap.w) * lrelu(z);
            z = bhi(lv.w)+bhi(rv.w); acc += bhi(ap.w) * lrelu(z);
        }
        aw[i] = __float_as_uint(acc);
    }
    __syncthreads();

    // ---- softmax per node: 4-lane quads, edges split 4/4/4/5 ----
    {
        const int node = tid >> 2, sub = tid & 3;
        if (node < NODES) {
            const int base = node*EPN + sub*4;
            float a0 = __uint_as_float(aw[base+0]);
            float a1 = __uint_as_float(aw[base+1]);
            float a2 = __uint_as_float(aw[base+2]);
            float a3 = __uint_as_float(aw[base+3]);
            const bool h5 = (sub == 3);
            float a4 = h5 ? __uint_as_float(aw[base+4]) : -1e30f;
            float m = fmaxf(fmaxf(fmaxf(a0,a1), fmaxf(a2,a3)), a4);
            m = fmaxf(m, __shfl_xor(m,1));
            m = fmaxf(m, __shfl_xor(m,2));
            a0 = __expf(a0-m); a1 = __expf(a1-m); a2 = __expf(a2-m); a3 = __expf(a3-m);
            a4 = h5 ? __expf(a4-m) : 0.f;
            float ss = a0+a1+a2+a3+a4;
            ss += __shfl_xor(ss,1);
            ss += __shfl_xor(ss,2);
            const float inv = 1.f/(ss + 1e-16f);
            aw[base+0] = ((unsigned int)eS[base+0]<<16) | bf16r(a0*inv);
            aw[base+1] = ((unsigned int)eS[base+1]<<16) | bf16r(a1*inv);
            aw[base+2] = ((unsigned int)eS[base+2]<<16) | bf16r(a2*inv);
            aw[base+3] = ((unsigned int)eS[base+3]<<16) | bf16r(a3*inv);
            if (h5) aw[base+4] = ((unsigned int)eS[base+4]<<16) | bf16r(a4*inv);
        }
    }
    __syncthreads();

    // ---- aggregation: 16 lanes/node x 4 channels ----
    const int grp = l >> 4;
    const int cl  = r16 * 4;
    const float4 biasv = *(const float4*)(bias + cl);

    float sx=0.f, sy=0.f, sz=0.f, sw=0.f;
    float qx=0.f, qy=0.f, qz=0.f, qw=0.f;

#pragma unroll
    for (int pass = 0; pass < 4; ++pass) {
        const int node = pass*16 + wv*4 + grp;
        if (node < NODES) {
            float ax=0.f, ay=0.f, az=0.f, a3=0.f;
#pragma unroll
            for (int e = 0; e < EPN; ++e) {
                const unsigned int p = aw[node*EPN + e];
                const float w = __uint_as_float(p << 16);
                const int s = (int)(p >> 16);
                const uint2 xv = *(const uint2*)(xlb + s*XS + cl);
                ax += w*blo(xv.x); ay += w*bhi(xv.x);
                az += w*blo(xv.y); a3 += w*bhi(xv.y);
            }
            ax += biasv.x; ay += biasv.y; az += biasv.z; a3 += biasv.w;
            float4 hv; hv.x=ax; hv.y=ay; hv.z=az; hv.w=a3;
            *(float4*)(h + (size_t)(nbase + node)*HIDC + cl) = hv;
            sx+=ax; sy+=ay; sz+=az; sw+=a3;
            qx+=ax*ax; qy+=ay*ay; qz+=az*az; qw+=a3*a3;
        }
    }

    // ---- BN partials ----
    sx += __shfl_xor(sx,16); sx += __shfl_xor(sx,32);
    sy += __shfl_xor(sy,16); sy += __shfl_xor(sy,32);
    sz += __shfl_xor(sz,16); sz += __shfl_xor(sz,32);
    sw += __shfl_xor(sw,16); sw += __shfl_xor(sw,32);
    qx += __shfl_xor(qx,16); qx += __shfl_xor(qx,32);
    qy += __shfl_xor(qy,16); qy += __shfl_xor(qy,32);
    qz += __shfl_xor(qz,16); qz += __shfl_xor(qz,32);
    qw += __shfl_xor(qw,16); qw += __shfl_xor(qw,32);
    if (l < 16) {
        red[0][wv][r16][0]=sx; red[0][wv][r16][1]=sy; red[0][wv][r16][2]=sz; red[0][wv][r16][3]=sw;
        red[1][wv][r16][0]=qx; red[1][wv][r16][1]=qy; red[1][wv][r16][2]=qz; red[1][wv][r16][3]=qw;
    }
    __syncthreads();
    if (tid < 128) {                       // part g-major: coalesced 512B store
        const int t = tid & 63, sel = tid >> 6, li = t >> 2, co = t & 3;
        const float s = red[sel][0][li][co] + red[sel][1][li][co]
                      + red[sel][2][li][co] + red[sel][3][li][co];
        part[(size_t)g*128 + tid] = s;
    }
}

// ---------------------------------------------------------------------------
// Kernel B1: stage-1 BN reduce. 64 blocks x 256 thr; block b sums 64 graphs.
// ---------------------------------------------------------------------------
__global__ __launch_bounds__(256) void bnred_kernel(
    const float* __restrict__ part, float* __restrict__ part2)
{
    __shared__ float red[2][128];
    const int b = blockIdx.x;
    const int ch = threadIdx.x & 127, rg = threadIdx.x >> 7;
    float s = 0.f;
    for (int r = rg; r < 64; r += 2)
        s += part[((size_t)b*64 + r)*128 + ch];
    red[rg][ch] = s;
    __syncthreads();
    if (threadIdx.x < 128)
        part2[(size_t)b*128 + threadIdx.x] = red[0][threadIdx.x] + red[1][threadIdx.x];
}

// ---------------------------------------------------------------------------
// Kernel B2: final fold. part2[64][128] -> BN folded into layer-2 weights.
// fw[0:64]=sc*Wl2, fw[64:128]=sc*Wr2, fw[128]=bl2', fw[129]=br2'
// ---------------------------------------------------------------------------
__global__ __launch_bounds__(256) void bnfold_kernel(
    const float* __restrict__ part2,
    const float* __restrict__ gamma, const float* __restrict__ beta,
    const float* __restrict__ Wl2, const float* __restrict__ bl2,
    const float* __restrict__ Wr2, const float* __restrict__ br2,
    float* __restrict__ fw)
{
    __shared__ float hred[2][128];
    __shared__ float gs[128];
    __shared__ float tmp[128];
    const int tid = threadIdx.x;
    const int ch = tid & 127, hg = tid >> 7;
    float s = 0.f;
    for (int r = hg; r < 64; r += 2) s += part2[(size_t)r*128 + ch];
    hred[hg][ch] = s;
    __syncthreads();
    if (tid < 128) gs[tid] = hred[0][tid] + hred[1][tid];
    __syncthreads();
    if (tid < HIDC) {
        const float invN = 1.f / (float)NTOT;
        const float mu  = gs[tid] * invN;
        const float var = gs[HIDC + tid] * invN - mu*mu;
        const float sc  = gamma[tid] * rsqrtf(var + 1e-5f);
        const float sh  = beta[tid] - mu * sc;
        fw[tid]        = sc * Wl2[tid];
        fw[HIDC + tid] = sc * Wr2[tid];
        tmp[tid]        = sh * Wl2[tid];
        tmp[HIDC + tid] = sh * Wr2[tid];
    }
    __syncthreads();
    if (tid < 64) {
        float aL = tmp[tid], aR = tmp[64 + tid];
#pragma unroll
        for (int msk = 1; msk < 64; msk <<= 1) {
            aL += __shfl_xor(aL, msk);
            aR += __shfl_xor(aR, msk);
        }
        if (tid == 0) { fw[128] = aL + bl2[0]; fw[129] = aR + br2[0]; }
    }
}

// ---------------------------------------------------------------------------
// Kernel C: GATv2 layer 2 + exact GELU. 4 graphs per block, one wave each.
// ---------------------------------------------------------------------------
__global__ __launch_bounds__(256, 4) void gat2_kernel(
    const float* __restrict__ h, const int* __restrict__ esrc,
    const float* __restrict__ fw, const float* __restrict__ att2,
    const float* __restrict__ bias2, float* __restrict__ out)
{
    __shared__ float fwL[130];
    __shared__ float xl2s[4][64], xr2s[4][64];
    __shared__ unsigned short srcs[4][NODES*DEG];

    const int tid = threadIdx.x;
    const int wv  = tid >> 6, l = tid & 63;
    const int g   = blockIdx.x*4 + wv;
    const int nbase = g * NODES;

    if (tid < 130) fwL[tid] = fw[tid];
    const int* eg = esrc + (size_t)nbase * DEG;
    for (int i = l; i < NODES*DEG; i += 64)
        srcs[wv][i] = (unsigned short)(eg[i] - nbase);
    __syncthreads();

    const int q = l >> 2, sub = l & 3;     // quad per node

    // xl2/xr2: quad handles node, 16ch per lane, 4 rounds
#pragma unroll
    for (int r = 0; r < 4; ++r) {
        const int n = r*16 + q;
        if (n < NODES) {
            const float4* hp = (const float4*)(h + (size_t)(nbase + n)*HIDC + sub*16);
            float al = 0.f, ar = 0.f;
#pragma unroll
            for (int t = 0; t < 4; ++t) {
                const float4 v = hp[t];
                const int cb = sub*16 + t*4;
                al += v.x*fwL[cb]   + v.y*fwL[cb+1]   + v.z*fwL[cb+2]   + v.w*fwL[cb+3];
                ar += v.x*fwL[64+cb]+ v.y*fwL[64+cb+1]+ v.z*fwL[64+cb+2]+ v.w*fwL[64+cb+3];
            }
            al += __shfl_xor(al,1); al += __shfl_xor(al,2);
            ar += __shfl_xor(ar,1); ar += __shfl_xor(ar,2);
            if (sub == 0) { xl2s[wv][n] = al + fwL[128]; xr2s[wv][n] = ar + fwL[129]; }
        }
    }
    __syncthreads();

    // attention + aggregation: quad per node, edges split 4/4/4/(4+self)
    const float a2v = att2[0];
    const float b2v = bias2[0];
#pragma unroll
    for (int r = 0; r < 4; ++r) {
        const int n = r*16 + q;
        if (n < NODES) {
            const float xr = xr2s[wv][n];
            const int jb = sub*4;
            const int s0 = srcs[wv][n*DEG + jb+0];
            const int s1 = srcs[wv][n*DEG + jb+1];
            const int s2 = srcs[wv][n*DEG + jb+2];
            const int s3 = srcs[wv][n*DEG + jb+3];
            const bool h5 = (sub == 3);
            const float x0 = xl2s[wv][s0], x1 = xl2s[wv][s1];
            const float x2 = xl2s[wv][s2], x3 = xl2s[wv][s3];
            const float x4 = xl2s[wv][n];                  // self loop
            const float v0 = lrelu(x0+xr)*a2v;
            const float v1 = lrelu(x1+xr)*a2v;
            const float v2 = lrelu(x2+xr)*a2v;
            const float v3 = lrelu(x3+xr)*a2v;
            const float v4 = h5 ? lrelu(x4+xr)*a2v : -1e30f;
            float m = fmaxf(fmaxf(fmaxf(v0,v1), fmaxf(v2,v3)), v4);
            m = fmaxf(m, __shfl_xor(m,1));
            m = fmaxf(m, __shfl_xor(m,2));
            const float e0 = __expf(v0-m), e1 = __expf(v1-m);
            const float e2 = __expf(v2-m), e3 = __expf(v3-m);
            const float e4 = h5 ? __expf(v4-m) : 0.f;
            float ss = e0+e1+e2+e3+e4;
            float ac = e0*x0 + e1*x1 + e2*x2 + e3*x3 + e4*x4;
            ss += __shfl_xor(ss,1); ss += __shfl_xor(ss,2);
            ac += __shfl_xor(ac,1); ac += __shfl_xor(ac,2);
            if (sub == 0) {
                const float o = ac/(ss + 1e-16f) + b2v;
                out[(size_t)g*NODES + n] = 0.5f*o*(1.f + erff(o*0.70710678118654752f));
            }
        }
    }
}

extern "C" void kernel_launch(void* const* d_in, const int* in_sizes, int n_in,
                              void* d_out, int out_size, void* d_ws, size_t ws_size,
                              hipStream_t stream) {
    const float* x     = (const float*)d_in[0];
    const int*   edge  = (const int*)d_in[1];     // [2,E]; src = first E
    const float* Wl1   = (const float*)d_in[2];
    const float* bl1   = (const float*)d_in[3];
    const float* Wr1   = (const float*)d_in[4];
    const float* br1   = (const float*)d_in[5];
    const float* att1  = (const float*)d_in[6];
    const float* bias1 = (const float*)d_in[7];
    const float* gamma = (const float*)d_in[8];
    const float* beta  = (const float*)d_in[9];
    const float* Wl2   = (const float*)d_in[10];
    const float* bl2   = (const float*)d_in[11];
    const float* Wr2   = (const float*)d_in[12];
    const float* br2   = (const float*)d_in[13];
    const float* att2  = (const float*)d_in[14];
    const float* bias2 = (const float*)d_in[15];
    float* out = (float*)d_out;

    float* h     = (float*)d_ws;                      // NTOT*64 floats
    float* part  = h + (size_t)NTOT * HIDC;           // 4096*128 floats, g-major
    float* part2 = part + (size_t)128 * NGRAPH;       // 64*128 floats
    float* fw    = part2 + (size_t)64 * 128;          // 130 floats

    gat1_kernel<<<NGRAPH, 256, 0, stream>>>(x, edge, Wl1, bl1, Wr1, br1,
                                            att1, bias1, h, part);
    bnred_kernel<<<64, 256, 0, stream>>>(part, part2);
    bnfold_kernel<<<1, 256, 0, stream>>>(part2, gamma, beta, Wl2, bl2, Wr2, br2, fw);
    gat2_kernel<<<NGRAPH/4, 256, 0, stream>>>(h, edge, fw, att2, bias2, out);
}